// Round 5
// baseline (260.451 us; speedup 1.0000x reference)
//
#include <hip/hip_runtime.h>

// Problem constants (fixed by setup_inputs): x is (1, 128, 128, 2048) fp32,
// channels-last. n=128 spatial, d=2048 channels.
constexpr int N_  = 128;
constexpr int D_  = 2048;
constexpr int NP_ = N_ * N_;      // 16384 spatial positions
constexpr int YB_ = 256;          // stage-A position-split blocks

// Native vector types (nontemporal builtins reject HIP_vector_type).
typedef float f32x4 __attribute__((ext_vector_type(4)));
typedef float f32x2 __attribute__((ext_vector_type(2)));

// Monotone float->uint mapping: preserves total order of floats (incl. negatives).
// Any finite float maps to >= 0x00800000 > 0, so 0-initialized accumulators lose.
__device__ __forceinline__ unsigned int fmap(float f) {
    unsigned int b = __float_as_uint(f);
    return (b & 0x80000000u) ? ~b : (b | 0x80000000u);
}

// Stage A: partial per-channel argmax. key = (fmap(v)<<32) | (NP-1-p):
// max key == max value, ties -> lowest flat index p (jnp.argmax semantics).
// Grid (2, 256): block = 256 threads x 4 channels (f32x4) x 64 positions.
// Writes partial[by][c] (4 MiB), coalesced 32 B/thread. No atomics, no memset.
__global__ __launch_bounds__(256)
void argmax_partial(const float* __restrict__ x,
                    unsigned long long* __restrict__ partial) {
    const int cIdx = blockIdx.x * 256 + threadIdx.x;   // f32x4 channel-group [0, 512)
    const int by   = blockIdx.y;
    const int p0   = by * (NP_ / YB_);
    const f32x4* __restrict__ x4 = (const f32x4*)x;

    unsigned long long b0 = 0, b1 = 0, b2 = 0, b3 = 0;
    #pragma unroll 8
    for (int p = p0; p < p0 + (NP_ / YB_); ++p) {
        // lanes read consecutive f32x4 -> 1 KiB coalesced per wave load;
        // this pass parks x in L3 for the apply pass.
        f32x4 v = x4[(size_t)p * (D_ / 4) + cIdx];
        unsigned long long lo = (unsigned long long)(unsigned int)(NP_ - 1 - p);
        unsigned long long k0 = ((unsigned long long)fmap(v.x) << 32) | lo;
        unsigned long long k1 = ((unsigned long long)fmap(v.y) << 32) | lo;
        unsigned long long k2 = ((unsigned long long)fmap(v.z) << 32) | lo;
        unsigned long long k3 = ((unsigned long long)fmap(v.w) << 32) | lo;
        b0 = max(b0, k0);
        b1 = max(b1, k1);
        b2 = max(b2, k2);
        b3 = max(b3, k3);
    }
    unsigned long long* dst = partial + (size_t)by * D_ + (size_t)cIdx * 4;
    dst[0] = b0; dst[1] = b1; dst[2] = b2; dst[3] = b3;
}

// Stage B: reduce 256 partials per channel, decode to float2 {i_max, j_max}.
// Reference's (deliberately transposed) decode: i_max = p % n, j_max = p / n.
// 32 blocks x 64 threads = 2048 threads (one per channel); reads coalesced.
__global__ __launch_bounds__(64)
void argmax_reduce(const unsigned long long* __restrict__ partial,
                   f32x2* __restrict__ maxpos) {
    const int c = blockIdx.x * 64 + threadIdx.x;       // channel [0, 2048)
    unsigned long long b = 0;
    #pragma unroll 8
    for (int by = 0; by < YB_; ++by)
        b = max(b, partial[(size_t)by * D_ + c]);
    unsigned int pm = (unsigned int)(NP_ - 1) - (unsigned int)(b & 0xFFFFFFFFull);
    f32x2 mp;
    mp.x = (float)(pm & 127);   // i_max = p % 128
    mp.y = (float)(pm >> 7);    // j_max = p / 128
    maxpos[c] = mp;
}

// Apply: mask = max(-1, 1 - (|i-i_max|+|j-j_max|)/128); out = x * mask.
// Grid-stride, 2048 blocks (8/CU), f32x4 in (cached: L3-resident from stage A),
// nt f32x4 out (never re-read). 16 KiB maxpos table is L1-resident.
__global__ __launch_bounds__(256)
void apply_kernel(const float* __restrict__ x,
                  const f32x2* __restrict__ maxpos,
                  float* __restrict__ out) {
    constexpr int TOTAL4 = NP_ * D_ / 4;               // 8,388,608
    constexpr int STRIDE = 2048 * 256;
    for (int g = blockIdx.x * 256 + threadIdx.x; g < TOTAL4; g += STRIDE) {
        const int e  = g * 4;                          // element index
        const int c4 = e & (D_ - 1);                   // channel base
        const int p  = e >> 11;                        // spatial flat index i*128+j
        const float fi = (float)(p >> 7);
        const float fj = (float)(p & 127);

        f32x4 v = ((const f32x4*)x)[g];
        f32x4 o;
        #pragma unroll
        for (int t = 0; t < 4; ++t) {
            f32x2 mp = maxpos[c4 + t];
            float l1 = fabsf(fi - mp.x) + fabsf(fj - mp.y);
            float m  = fmaxf(-1.0f, 1.0f - l1 * (1.0f / 128.0f));
            o[t] = v[t] * m;
        }
        __builtin_nontemporal_store(o, ((f32x4*)out) + g);
    }
}

extern "C" void kernel_launch(void* const* d_in, const int* in_sizes, int n_in,
                              void* d_out, int out_size, void* d_ws, size_t ws_size,
                              hipStream_t stream) {
    const float* x = (const float*)d_in[0];
    float* out = (float*)d_out;
    // ws layout: [0, 4 MiB) partial keys; [4 MiB, +16 KiB) maxpos table.
    unsigned long long* partial = (unsigned long long*)d_ws;
    f32x2* maxpos = (f32x2*)((char*)d_ws + (size_t)YB_ * D_ * sizeof(unsigned long long));

    argmax_partial<<<dim3(2, YB_), dim3(256), 0, stream>>>(x, partial);
    argmax_reduce<<<dim3(32), dim3(64), 0, stream>>>(partial, maxpos);
    apply_kernel<<<dim3(2048), dim3(256), 0, stream>>>(x, maxpos, out);
}

// Round 7
// 257.993 us; speedup vs baseline: 1.0095x; 1.0095x over previous
//
#include <hip/hip_runtime.h>

// Problem constants (fixed by setup_inputs): x is (1, 128, 128, 2048) fp32,
// channels-last. n=128 spatial, d=2048 channels.
constexpr int N_  = 128;
constexpr int D_  = 2048;
constexpr int NP_ = N_ * N_;      // 16384 spatial positions
constexpr int YB_ = 512;          // stage-A position-split blocks

// Native vector types (nontemporal builtins reject HIP_vector_type).
typedef float f32x4 __attribute__((ext_vector_type(4)));
typedef float f32x2 __attribute__((ext_vector_type(2)));

// Monotone float->uint mapping: preserves total order of floats (incl. negatives).
// Any finite float maps to >= 0x00800000 > 0, so 0-initialized accumulators lose.
__device__ __forceinline__ unsigned int fmap(float f) {
    unsigned int b = __float_as_uint(f);
    return (b & 0x80000000u) ? ~b : (b | 0x80000000u);
}

// Stage A: partial per-channel argmax. key = (fmap(v)<<32) | (NP-1-p):
// max key == max value, ties -> lowest flat index p (jnp.argmax semantics).
// Grid (2, 512) = 1024 blocks (4/CU, 4 waves/SIMD): 256 threads x 4 channels
// (f32x4) x 32 positions. Writes partial[by][c] (8 MiB), coalesced, no atomics.
__global__ __launch_bounds__(256)
void argmax_partial(const float* __restrict__ x,
                    unsigned long long* __restrict__ partial) {
    const int cIdx = blockIdx.x * 256 + threadIdx.x;   // f32x4 channel-group [0, 512)
    const int by   = blockIdx.y;
    const int p0   = by * (NP_ / YB_);
    const f32x4* __restrict__ x4 = (const f32x4*)x;

    unsigned long long b0 = 0, b1 = 0, b2 = 0, b3 = 0;
    #pragma unroll 8
    for (int p = p0; p < p0 + (NP_ / YB_); ++p) {
        // lanes read consecutive f32x4 -> 1 KiB coalesced per wave load;
        // this pass parks x in L3 for the apply pass.
        f32x4 v = x4[(size_t)p * (D_ / 4) + cIdx];
        unsigned long long lo = (unsigned long long)(unsigned int)(NP_ - 1 - p);
        unsigned long long k0 = ((unsigned long long)fmap(v.x) << 32) | lo;
        unsigned long long k1 = ((unsigned long long)fmap(v.y) << 32) | lo;
        unsigned long long k2 = ((unsigned long long)fmap(v.z) << 32) | lo;
        unsigned long long k3 = ((unsigned long long)fmap(v.w) << 32) | lo;
        b0 = max(b0, k0);
        b1 = max(b1, k1);
        b2 = max(b2, k2);
        b3 = max(b3, k3);
    }
    unsigned long long* dst = partial + (size_t)by * D_ + (size_t)cIdx * 4;
    dst[0] = b0; dst[1] = b1; dst[2] = b2; dst[3] = b3;
}

// Stage B: reduce YB_ partials per channel, decode to float2 {i_max, j_max}.
// Reference's (deliberately transposed) decode: i_max = p % n, j_max = p / n.
// 32 blocks x 256 threads: block owns 64 channels; 4 threads/channel split the
// by-range 4-way, LDS tree-merge. Reads coalesced (64 lanes x 8 B consecutive).
__global__ __launch_bounds__(256)
void argmax_reduce(const unsigned long long* __restrict__ partial,
                   f32x2* __restrict__ maxpos) {
    const int lane = threadIdx.x & 63;                 // channel-in-block
    const int q    = threadIdx.x >> 6;                 // by-quarter [0,4)
    const int c    = blockIdx.x * 64 + lane;           // channel [0, 2048)

    unsigned long long b = 0;
    #pragma unroll 8
    for (int by = q * (YB_ / 4); by < (q + 1) * (YB_ / 4); ++by)
        b = max(b, partial[(size_t)by * D_ + c]);

    __shared__ unsigned long long red[4][64];
    red[q][lane] = b;
    __syncthreads();
    if (q == 0) {
        b = max(max(red[0][lane], red[1][lane]), max(red[2][lane], red[3][lane]));
        unsigned int pm = (unsigned int)(NP_ - 1) - (unsigned int)(b & 0xFFFFFFFFull);
        f32x2 mp;
        mp.x = (float)(pm & 127);   // i_max = p % 128
        mp.y = (float)(pm >> 7);    // j_max = p / 128
        maxpos[c] = mp;
    }
}

// Apply: mask = max(-1, 1 - (|i-i_max|+|j-j_max|)/128); out = x * mask.
// 2048 blocks x 256 threads, 8 elements/thread (2x f32x4), exactly 8 iters.
// x read cached (L3-resident from stage A); out streamed with nt stores.
// maxpos fetched as 4x f32x4 (= 4 channel-pairs) from the 16 KiB L1-resident table.
__global__ __launch_bounds__(256)
void apply_kernel(const float* __restrict__ x,
                  const f32x2* __restrict__ maxpos,
                  float* __restrict__ out) {
    constexpr int TOTAL8 = NP_ * D_ / 8;               // 4,194,304
    constexpr int STRIDE = 2048 * 256;
    const f32x4* __restrict__ x4  = (const f32x4*)x;
    const f32x4* __restrict__ mp4 = (const f32x4*)maxpos;  // {i0,j0,i1,j1} per load
    f32x4* __restrict__ out4 = (f32x4*)out;

    for (int g = blockIdx.x * 256 + threadIdx.x; g < TOTAL8; g += STRIDE) {
        const int e  = g * 8;                          // element index (8-aligned)
        const int c8 = e & (D_ - 1);                   // channel base (mult of 8)
        const int p  = e >> 11;                        // spatial flat index i*128+j
        const float fi = (float)(p >> 7);
        const float fj = (float)(p & 127);

        f32x4 v0 = x4[g * 2];
        f32x4 v1 = x4[g * 2 + 1];

        f32x4 o0, o1;
        #pragma unroll
        for (int t = 0; t < 4; ++t) {                  // t-th channel pair
            f32x4 mp = mp4[(c8 >> 1) + t];             // {imax0,jmax0,imax1,jmax1}
            float l1a = fabsf(fi - mp.x) + fabsf(fj - mp.y);
            float l1b = fabsf(fi - mp.z) + fabsf(fj - mp.w);
            float ma = fmaxf(-1.0f, 1.0f - l1a * (1.0f / 128.0f));
            float mb = fmaxf(-1.0f, 1.0f - l1b * (1.0f / 128.0f));
            if (t < 2) {
                o0[2 * t]     = v0[2 * t]     * ma;
                o0[2 * t + 1] = v0[2 * t + 1] * mb;
            } else {
                o1[2 * t - 4] = v1[2 * t - 4] * ma;
                o1[2 * t - 3] = v1[2 * t - 3] * mb;
            }
        }
        __builtin_nontemporal_store(o0, out4 + g * 2);
        __builtin_nontemporal_store(o1, out4 + g * 2 + 1);
    }
}

extern "C" void kernel_launch(void* const* d_in, const int* in_sizes, int n_in,
                              void* d_out, int out_size, void* d_ws, size_t ws_size,
                              hipStream_t stream) {
    const float* x = (const float*)d_in[0];
    float* out = (float*)d_out;
    // ws layout: [0, 8 MiB) partial keys; [8 MiB, +16 KiB) maxpos table.
    unsigned long long* partial = (unsigned long long*)d_ws;
    f32x2* maxpos = (f32x2*)((char*)d_ws + (size_t)YB_ * D_ * sizeof(unsigned long long));

    argmax_partial<<<dim3(2, YB_), dim3(256), 0, stream>>>(x, partial);
    argmax_reduce<<<dim3(32), dim3(256), 0, stream>>>(partial, maxpos);
    apply_kernel<<<dim3(2048), dim3(256), 0, stream>>>(x, maxpos, out);
}